// Round 1
// baseline (670.134 us; speedup 1.0000x reference)
//
#include <hip/hip_runtime.h>

namespace {

constexpr int Dn   = 128;   // model dim
constexpr int DIN  = 512;   // input / output dim
constexpr int Hn   = 8;     // heads
constexpr int Mn   = 128;   // memory slots
constexpr int DFF  = 512;   // ff dim
constexpr int Gn   = 8;     // batches per block
constexpr int TR   = 16;    // mem rows per streamed tile
constexpr int NTILE = Mn / TR;           // 8
constexpr int DP   = 132;   // padded LDS row (floats) -> breaks bank conflicts
constexpr float ATT_SCALE = 0.25f;
constexpr float INV_SQRT2 = 0.70710678118654752440f;

// dot of a 128-float global row with a 128-float LDS vector
__device__ __forceinline__ float dot128(const float* __restrict__ wrow,
                                        const float* __restrict__ v)
{
    const float4* w4 = (const float4*)wrow;
    const float4* v4 = (const float4*)v;
    float acc = 0.f;
#pragma unroll
    for (int j = 0; j < 32; ++j) {
        float4 a = w4[j], b = v4[j];
        acc += a.x*b.x + a.y*b.y + a.z*b.z + a.w*b.w;
    }
    return acc;
}

// LayerNorm of Gn rows x NCOL cols, 32 threads per row (t>>5 = row, t&31 = sub).
// In-place (src==dst) is safe: each thread rewrites only its own elements.
template <int NCOL>
__device__ __forceinline__ void ln_row_32(const float* __restrict__ src,
                                          float* __restrict__ dst,
                                          const float* __restrict__ gw,
                                          const float* __restrict__ gb,
                                          const float* __restrict__ resid,
                                          int sub)
{
    constexpr int E = NCOL / 32;
    float v0[E]; float sm = 0.f;
#pragma unroll
    for (int i = 0; i < E; ++i) { v0[i] = src[sub*E + i]; sm += v0[i]; }
#pragma unroll
    for (int m = 16; m >= 1; m >>= 1) sm += __shfl_xor(sm, m);
    float mean = sm * (1.f / (float)NCOL);
    float vs = 0.f;
#pragma unroll
    for (int i = 0; i < E; ++i) { float d0 = v0[i] - mean; vs += d0*d0; }
#pragma unroll
    for (int m = 16; m >= 1; m >>= 1) vs += __shfl_xor(vs, m);
    float rstd = rsqrtf(vs * (1.f / (float)NCOL) + 1e-5f);
#pragma unroll
    for (int i = 0; i < E; ++i) {
        int d = sub*E + i;
        float r = (v0[i] - mean) * rstd * gw[d] + gb[d];
        dst[d] = resid ? (r + resid[d]) : r;
    }
}

__global__ __launch_bounds__(256, 2)
void fused_block(const float* __restrict__ x,
                 const float* __restrict__ W_in,
                 const float* __restrict__ b_in,
                 const float* __restrict__ pos,
                 const float* __restrict__ mask,
                 const float* __restrict__ mem,
                 const float* __restrict__ ln1_w, const float* __restrict__ ln1_b,
                 const float* __restrict__ W_qkv, const float* __restrict__ b_qkv,
                 const float* __restrict__ W_out, const float* __restrict__ b_out,
                 const float* __restrict__ ln2_w, const float* __restrict__ ln2_b,
                 const float* __restrict__ ln3_w, const float* __restrict__ ln3_b,
                 const float* __restrict__ W_ff1, const float* __restrict__ b_ff1,
                 const float* __restrict__ ln4_w, const float* __restrict__ ln4_b,
                 const float* __restrict__ W_ff2, const float* __restrict__ b_ff2,
                 const float* __restrict__ ln5_w, const float* __restrict__ ln5_b,
                 const float* __restrict__ W_head, const float* __restrict__ b_head,
                 float* __restrict__ out)
{
    const int t  = threadIdx.x;
    const int b0 = blockIdx.x * Gn;

    __shared__ __align__(16) float s_qin[Gn][Dn];
    __shared__ __align__(16) float s_lnq[Gn][Dn];
    __shared__ __align__(16) float s_qo [Gn][Dn];   // q, later o
    __shared__ __align__(16) float s_h  [Gn][Dn];
    __shared__ __align__(16) float s_ch [Gn][Hn];
    __shared__ __align__(16) union {
        float xrow[Gn][DIN];                 // 16 KB   (P0/P1)
        struct {                             // ~47 KB  (attention)
            float Aq[Gn][Hn][DP];
            float tile[TR][DP];
            float sc[Hn][TR];
            float ctx[Hn][DP];
            float mh[Hn], denh[Hn], fh[Hn];
        } at;
        struct {                             // 20 KB   (MLP tail)
            float f1[Gn][DFF];
            float tmp[Gn][Dn];
        } ff;
    } u;

    //--- P0: stage x rows -------------------------------------------------
    {
        const float4* src = (const float4*)(x + (size_t)b0 * DIN);
        float4* dst = (float4*)&u.xrow[0][0];
#pragma unroll
        for (int i = 0; i < (Gn*DIN/4)/256; ++i)
            dst[t + i*256] = src[t + i*256];
    }
    __syncthreads();

    //--- P1: q_in = x @ W_in^T + b_in + pos -------------------------------
    for (int idx = t; idx < Gn*Dn; idx += 256) {
        int g = idx >> 7, d = idx & 127;
        const float4* w4 = (const float4*)(W_in + (size_t)d * DIN);
        const float4* x4 = (const float4*)&u.xrow[g][0];
        float acc = 0.f;
#pragma unroll 8
        for (int j = 0; j < DIN/4; ++j) {
            float4 a = w4[j], b = x4[j];
            acc += a.x*b.x + a.y*b.y + a.z*b.z + a.w*b.w;
        }
        s_qin[g][d] = acc + b_in[d] + pos[(size_t)(b0+g)*Dn + d];
    }
    __syncthreads();

    //--- P2: lnq = LN(q_in, ln1)  (kv row 0) ------------------------------
    ln_row_32<Dn>(&s_qin[t>>5][0], &s_lnq[t>>5][0], ln1_w, ln1_b, nullptr, t & 31);
    __syncthreads();

    //--- P3: q = q_in @ Wq^T + bq  (into s_qo) ----------------------------
    for (int idx = t; idx < Gn*Dn; idx += 256) {
        int g = idx >> 7, d = idx & 127;
        s_qo[g][d] = dot128(W_qkv + (size_t)d*Dn, &s_qin[g][0]) + b_qkv[d];
    }
    __syncthreads();

    //--- P4: Aq[g][h][:] = SCALE * q_h @ Wk_h ;  ch[g][h] -----------------
    for (int idx = t; idx < Gn*Hn*Dn; idx += 256) {
        int j = idx & 127, hh = (idx >> 7) & 7, g = idx >> 10;
        float acc = 0.f;
#pragma unroll
        for (int d0 = 0; d0 < 16; ++d0)
            acc += s_qo[g][hh*16 + d0] * W_qkv[(size_t)(Dn + hh*16 + d0)*Dn + j];
        u.at.Aq[g][hh][j] = ATT_SCALE * acc;
    }
    if (t < Gn*Hn) {
        int g = t >> 3, hh = t & 7;
        float acc = 0.f;
#pragma unroll
        for (int d0 = 0; d0 < 16; ++d0)
            acc += s_qo[g][hh*16 + d0] * b_qkv[Dn + hh*16 + d0];
        s_ch[g][hh] = ATT_SCALE * acc;
    }
    __syncthreads();

    //--- P5: streamed attention with online softmax -----------------------
    float4 pr0, pr1;   // register prefetch of next 16x128 mem tile
    {
        const float4* src = (const float4*)(mem + (size_t)b0 * Mn * Dn);
        pr0 = src[t]; pr1 = src[t + 256];
    }
    for (int it = 0; it < Gn * NTILE; ++it) {
        const int g = it >> 3, T = it & 7;
        const int b = b0 + g;

        if (T == 0) {
            // init running state with kv row l=0 (= lnq, bias 0)
            int hh = t >> 5, sub = t & 31;
            float acc = 0.f;
#pragma unroll
            for (int i = 0; i < 4; ++i)
                acc += u.at.Aq[g][hh][sub*4 + i] * s_lnq[g][sub*4 + i];
#pragma unroll
            for (int m = 16; m >= 1; m >>= 1) acc += __shfl_xor(acc, m);
            if (sub == 0) { u.at.mh[hh] = acc + s_ch[g][hh]; u.at.denh[hh] = 1.f; }
            for (int idx = t; idx < Hn*Dn; idx += 256) {
                int h2 = idx >> 7, j = idx & 127;
                u.at.ctx[h2][j] = s_lnq[g][j];
            }
        }

        // write prefetched tile into LDS (padded rows)
        {
            ((float4*)&u.at.tile[t >> 5][0])[t & 31] = pr0;
            int t2 = t + 256;
            ((float4*)&u.at.tile[t2 >> 5][0])[t2 & 31] = pr1;
        }
        // issue next tile's loads (complete under this tile's compute)
        if (it + 1 < Gn * NTILE) {
            int g2 = (it+1) >> 3, T2 = (it+1) & 7;
            const float4* src = (const float4*)(mem + ((size_t)(b0+g2)*Mn + (size_t)T2*TR) * Dn);
            pr0 = src[t]; pr1 = src[t + 256];
        }
        __syncthreads();

        // LN(ln1) of the 16 tile rows, in place; 16 threads per row
        {
            int r = t >> 4, sub = t & 15;
            float v0[8]; float sm = 0.f;
#pragma unroll
            for (int i = 0; i < 8; ++i) { v0[i] = u.at.tile[r][sub*8 + i]; sm += v0[i]; }
#pragma unroll
            for (int m = 8; m >= 1; m >>= 1) sm += __shfl_xor(sm, m);
            float mean = sm * (1.f/128.f);
            float vs = 0.f;
#pragma unroll
            for (int i = 0; i < 8; ++i) { float d0 = v0[i] - mean; vs += d0*d0; }
#pragma unroll
            for (int m = 8; m >= 1; m >>= 1) vs += __shfl_xor(vs, m);
            float rstd = rsqrtf(vs * (1.f/128.f) + 1e-5f);
#pragma unroll
            for (int i = 0; i < 8; ++i) {
                int d = sub*8 + i;
                u.at.tile[r][d] = (v0[i] - mean) * rstd * ln1_w[d] + ln1_b[d];
            }
        }
        __syncthreads();

        // scores + online softmax update (128 threads: h x r)
        if (t < Hn*TR) {
            int hh = t >> 4, r = t & 15;
            const float4* a4 = (const float4*)&u.at.Aq[g][hh][0];
            const float4* r4 = (const float4*)&u.at.tile[r][0];
            float acc = 0.f;
#pragma unroll
            for (int j = 0; j < 32; ++j) {
                float4 a = a4[j], c = r4[j];
                acc += a.x*c.x + a.y*c.y + a.z*c.z + a.w*c.w;
            }
            float sval = acc + s_ch[g][hh] + mask[(size_t)b*Mn + T*TR + r];
            float tm = sval;
#pragma unroll
            for (int m = 8; m >= 1; m >>= 1) tm = fmaxf(tm, __shfl_xor(tm, m));
            float oldm = u.at.mh[hh];
            float newm = fmaxf(oldm, tm);
            float p  = __expf(sval - newm);
            float ps = p;
#pragma unroll
            for (int m = 8; m >= 1; m >>= 1) ps += __shfl_xor(ps, m);
            u.at.sc[hh][r] = p;
            if (r == 0) {
                float f = __expf(oldm - newm);
                u.at.fh[hh]   = f;
                u.at.mh[hh]   = newm;
                u.at.denh[hh] = u.at.denh[hh]*f + ps;
            }
        }
        __syncthreads();

        // ctx = ctx*fh + p @ ln_tile
        for (int idx = t; idx < Hn*Dn; idx += 256) {
            int hh = idx >> 7, j = idx & 127;
            float c0 = u.at.ctx[hh][j] * u.at.fh[hh];
#pragma unroll
            for (int r = 0; r < TR; ++r)
                c0 += u.at.sc[hh][r] * u.at.tile[r][j];
            u.at.ctx[hh][j] = c0;
        }
        __syncthreads();

        if (T == NTILE-1) {
            // o = Wv @ (ctx/den) + bv    (Wv folded over the p-weighted context)
            if (t < Dn) {
                int i = t, hh = i >> 4;
                const float4* w4 = (const float4*)(W_qkv + (size_t)(2*Dn + i)*Dn);
                const float4* c4 = (const float4*)&u.at.ctx[hh][0];
                float acc = 0.f;
#pragma unroll
                for (int j = 0; j < 32; ++j) {
                    float4 a = w4[j], c = c4[j];
                    acc += a.x*c.x + a.y*c.y + a.z*c.z + a.w*c.w;
                }
                s_qo[g][i] = acc / u.at.denh[hh] + b_qkv[2*Dn + i];
            }
            __syncthreads();
        }
    }

    //--- P6a: t1 = o @ W_out^T + b_out ------------------------------------
    for (int idx = t; idx < Gn*Dn; idx += 256) {
        int g = idx >> 7, d = idx & 127;
        u.ff.tmp[g][d] = dot128(W_out + (size_t)d*Dn, &s_qo[g][0]) + b_out[d];
    }
    __syncthreads();

    //--- P6b: h = LN(t1, ln2) + q_in --------------------------------------
    ln_row_32<Dn>(&u.ff.tmp[t>>5][0], &s_h[t>>5][0], ln2_w, ln2_b, &s_qin[t>>5][0], t & 31);
    __syncthreads();

    //--- P6c: ln3h = LN(h, ln3) -> tmp ------------------------------------
    ln_row_32<Dn>(&s_h[t>>5][0], &u.ff.tmp[t>>5][0], ln3_w, ln3_b, nullptr, t & 31);
    __syncthreads();

    //--- P6d: f1 = gelu(ln3h @ W_ff1^T + b_ff1) ---------------------------
    for (int idx = t; idx < Gn*DFF; idx += 256) {
        int g = idx >> 9, e = idx & 511;
        float val = dot128(W_ff1 + (size_t)e*Dn, &u.ff.tmp[g][0]) + b_ff1[e];
        u.ff.f1[g][e] = 0.5f * val * (1.f + erff(val * INV_SQRT2));
    }
    __syncthreads();

    //--- P6e: LN(f1, ln4) in place ----------------------------------------
    ln_row_32<DFF>(&u.ff.f1[t>>5][0], &u.ff.f1[t>>5][0], ln4_w, ln4_b, nullptr, t & 31);
    __syncthreads();

    //--- P6f: f2h = f1 @ W_ff2^T + b_ff2 + h -> tmp -----------------------
    for (int idx = t; idx < Gn*Dn; idx += 256) {
        int g = idx >> 7, d = idx & 127;
        const float4* w4 = (const float4*)(W_ff2 + (size_t)d*DFF);
        const float4* v4 = (const float4*)&u.ff.f1[g][0];
        float acc = 0.f;
#pragma unroll 8
        for (int j = 0; j < DFF/4; ++j) {
            float4 a = w4[j], c = v4[j];
            acc += a.x*c.x + a.y*c.y + a.z*c.z + a.w*c.w;
        }
        u.ff.tmp[g][d] = acc + b_ff2[d] + s_h[g][d];
    }
    __syncthreads();

    //--- P6g: h2 = LN(tmp, ln5) -> s_qo -----------------------------------
    ln_row_32<Dn>(&u.ff.tmp[t>>5][0], &s_qo[t>>5][0], ln5_w, ln5_b, nullptr, t & 31);
    __syncthreads();

    //--- P6h: out = h2 @ W_head^T + b_head --------------------------------
    for (int idx = t; idx < Gn*DIN; idx += 256) {
        int g = idx >> 9, e = idx & 511;
        out[(size_t)(b0+g)*DIN + e] = dot128(W_head + (size_t)e*Dn, &s_qo[g][0]) + b_head[e];
    }
}

} // namespace

extern "C" void kernel_launch(void* const* d_in, const int* in_sizes, int n_in,
                              void* d_out, int out_size, void* d_ws, size_t ws_size,
                              hipStream_t stream)
{
    const float* x      = (const float*)d_in[0];
    const float* W_in   = (const float*)d_in[1];
    const float* b_in   = (const float*)d_in[2];
    const float* pos    = (const float*)d_in[3];
    const float* mask   = (const float*)d_in[4];
    const float* mem    = (const float*)d_in[5];
    const float* ln1_w  = (const float*)d_in[6];
    const float* ln1_b  = (const float*)d_in[7];
    const float* W_qkv  = (const float*)d_in[8];
    const float* b_qkv  = (const float*)d_in[9];
    const float* W_out  = (const float*)d_in[10];
    const float* b_out  = (const float*)d_in[11];
    const float* ln2_w  = (const float*)d_in[12];
    const float* ln2_b  = (const float*)d_in[13];
    const float* ln3_w  = (const float*)d_in[14];
    const float* ln3_b  = (const float*)d_in[15];
    const float* W_ff1  = (const float*)d_in[16];
    const float* b_ff1  = (const float*)d_in[17];
    const float* ln4_w  = (const float*)d_in[18];
    const float* ln4_b  = (const float*)d_in[19];
    const float* W_ff2  = (const float*)d_in[20];
    const float* b_ff2  = (const float*)d_in[21];
    const float* ln5_w  = (const float*)d_in[22];
    const float* ln5_b  = (const float*)d_in[23];
    const float* W_head = (const float*)d_in[24];
    const float* b_head = (const float*)d_in[25];

    const int B = in_sizes[0] / DIN;   // 4096
    fused_block<<<dim3(B / Gn), dim3(256), 0, stream>>>(
        x, W_in, b_in, pos, mask, mem,
        ln1_w, ln1_b, W_qkv, b_qkv, W_out, b_out,
        ln2_w, ln2_b, ln3_w, ln3_b,
        W_ff1, b_ff1, ln4_w, ln4_b, W_ff2, b_ff2,
        ln5_w, ln5_b, W_head, b_head,
        (float*)d_out);
}